// Round 2
// baseline (256.563 us; speedup 1.0000x reference)
//
#include <hip/hip_runtime.h>
#include <math.h>

// Random_frequency_replacing: out = clean + IFFT2( sel_b(k) * FFT2(noisy - clean) )
// where sel_b(k) = value_set[(b+8)%16, band(|k|)] (0/1), band from radial bucketize,
// derived from fftshift/ifftshift cancellation (full-axes torch-style shifts only
// remap the mask; batch axis shift -> value_set row (b+8)%16).
//
// B=16, C=3, H=W=512 -> 48 images. 512-pt FFT = radix-8 Stockham, 3 stages,
// one wave (64 lanes) per FFT, LDS scratch private per wave (no barriers:
// a wave is a single instruction stream).

using cplx = float2;

__device__ __forceinline__ cplx cmul(cplx a, cplx b){
  return make_float2(a.x*b.x - a.y*b.y, a.x*b.y + a.y*b.x);
}
__device__ __forceinline__ cplx cadd(cplx a, cplx b){ return make_float2(a.x+b.x, a.y+b.y); }
__device__ __forceinline__ cplx csub(cplx a, cplx b){ return make_float2(a.x-b.x, a.y-b.y); }
// multiply by S*i  (S=-1: a*(-i), S=+1: a*(+i))
template<int S> __device__ __forceinline__ cplx muli(cplx a){
  return (S < 0) ? make_float2(a.y, -a.x) : make_float2(-a.y, a.x);
}
// XOR swizzle on 512-entry float2 scratch: mixes idx[8:6] into idx[3:1] to break
// the stride-8 write pattern's bank conflicts (involution, bijective on 0..511).
__device__ __forceinline__ int sw(int i){ return i ^ (((i >> 6) & 7) << 1); }

// natural-order DFT-8, sign S (-1 fwd, +1 inv), DIT decomposition
template<int S>
__device__ __forceinline__ void dft8(cplx v[8]){
  const float R2 = 0.70710678118654752440f;
  cplx e0 = cadd(v[0], v[4]), e1 = csub(v[0], v[4]);
  cplx o0 = cadd(v[2], v[6]), o1 = muli<S>(csub(v[2], v[6]));
  cplx E0 = cadd(e0, o0), E1 = cadd(e1, o1), E2 = csub(e0, o0), E3 = csub(e1, o1);
  cplx f0 = cadd(v[1], v[5]), f1 = csub(v[1], v[5]);
  cplx g0 = cadd(v[3], v[7]), g1 = muli<S>(csub(v[3], v[7]));
  cplx F0 = cadd(f0, g0), F1 = cadd(f1, g1), F2 = csub(f0, g0), F3 = csub(f1, g1);
  const cplx w1 = make_float2( R2, (float)S * R2);   // W8^1 (sign S)
  const cplx w3 = make_float2(-R2, (float)S * R2);   // W8^3
  cplx t0 = F0, t1 = cmul(w1, F1), t2 = muli<S>(F2), t3 = cmul(w3, F3);
  v[0] = cadd(E0, t0); v[4] = csub(E0, t0);
  v[1] = cadd(E1, t1); v[5] = csub(E1, t1);
  v[2] = cadd(E2, t2); v[6] = csub(E2, t2);
  v[3] = cadd(E3, t3); v[7] = csub(E3, t3);
}

// v[r] *= exp(i * ang * r), r=0..7
__device__ __forceinline__ void twiddle8(cplx v[8], float ang){
  float sn, cs; __sincosf(ang, &sn, &cs);
  cplx w = make_float2(cs, sn), cur = w;
  #pragma unroll
  for(int r = 1; r < 8; r++){ v[r] = cmul(v[r], cur); cur = cmul(cur, w); }
}

// 512-pt Stockham FFT, radix 8, 3 stages. t = lane (0..63).
// in : v[r] = x[t + 64r]   out: v[r] = X[t + 64r]
// s = per-wave 512-entry LDS scratch.
template<int S>
__device__ __forceinline__ void fft512(cplx v[8], cplx* s, int t){
  const float PI2 = 6.283185307179586f;
  // stage 0 (Ns=1): no twiddle
  dft8<S>(v);
  #pragma unroll
  for(int r = 0; r < 8; r++) s[sw(t*8 + r)] = v[r];
  // stage 1 (Ns=8)
  #pragma unroll
  for(int r = 0; r < 8; r++) v[r] = s[sw(t + 64*r)];
  twiddle8(v, (float)S * PI2 * (1.0f/64.0f) * (float)(t & 7));
  dft8<S>(v);
  int d1 = ((t >> 3) << 6) | (t & 7);
  #pragma unroll
  for(int r = 0; r < 8; r++) s[sw(d1 + (r << 3))] = v[r];
  // stage 2 (Ns=64): result stays in registers
  #pragma unroll
  for(int r = 0; r < 8; r++) v[r] = s[sw(t + 64*r)];
  twiddle8(v, (float)S * PI2 * (1.0f/512.0f) * (float)t);
  dft8<S>(v);
}

// ---------------- K1: row FFT of (noisy - clean) -> ws ----------------
__global__ __launch_bounds__(256) void k_rowfft(const float* __restrict__ noisy,
                                                const float* __restrict__ clean,
                                                float2* __restrict__ ws){
  __shared__ cplx sbuf[4][512];
  int wid = threadIdx.x >> 6, t = threadIdx.x & 63;
  size_t row = (size_t)blockIdx.x * 4 + wid;        // 0 .. 48*512-1
  const float* np_ = noisy + row * 512;
  const float* cp_ = clean + row * 512;
  cplx v[8];
  #pragma unroll
  for(int r = 0; r < 8; r++){ int i = t + 64*r; v[r] = make_float2(np_[i] - cp_[i], 0.0f); }
  fft512<-1>(v, sbuf[wid], t);
  float2* op = ws + row * 512;
  #pragma unroll
  for(int r = 0; r < 8; r++) op[t + 64*r] = v[r];
}

// ------- K2: column FFT + radial 0/1 mask (*1/N^2) + column IFFT, in place -------
#define INV_BAND 0.27621358640099513f   // 100 / (sqrt(512^2+512^2)/2)

__global__ __launch_bounds__(256) void k_colfft(float2* __restrict__ ws,
                                                const float* __restrict__ value_set){
  __shared__ cplx tile[512][9];   // 8 columns, +1 pad (36,864 B)
  __shared__ cplx scr[4][512];    // per-wave FFT scratch (16,384 B)
  int img = blockIdx.x >> 6;                 // 0..47
  int w0  = (blockIdx.x & 63) << 3;          // first of 8 columns
  int b   = img / 3;
  const float* vs = value_set + ((b + 8) & 15) * 100;   // batch fftshift remap
  float2* base = ws + (size_t)img * (512 * 512);

  // cooperative coalesced load of 512 x 8 complex tile
  #pragma unroll
  for(int h0 = 0; h0 < 512; h0 += 32){
    int h = h0 + (threadIdx.x >> 3), j = threadIdx.x & 7;
    tile[h][j] = base[(size_t)h * 512 + w0 + j];
  }
  __syncthreads();

  int wid = threadIdx.x >> 6, t = threadIdx.x & 63;
  #pragma unroll 1
  for(int jj = 0; jj < 2; jj++){
    int j = (wid << 1) | jj;                 // each wave owns 2 columns
    int w = w0 + j;
    int fw = (w < 256) ? w : w - 512;
    int fw2 = fw * fw;
    cplx v[8];
    #pragma unroll
    for(int r = 0; r < 8; r++) v[r] = tile[t + 64*r][j];
    fft512<-1>(v, scr[wid], t);
    // mask: band = floor(r * 100/max_radius); sel in {0,1}; fold in 1/(H*W)
    #pragma unroll
    for(int r = 0; r < 8; r++){
      int h = t + 64*r;
      int fh = (h < 256) ? h : h - 512;
      float rr = sqrtf((float)(fh*fh + fw2));
      int idx = (int)(rr * INV_BAND);
      float sel = (idx < 100) ? vs[idx] : 0.0f;
      float sc = sel * (1.0f / 262144.0f);
      v[r].x *= sc; v[r].y *= sc;
    }
    fft512<1>(v, scr[wid], t);
    #pragma unroll
    for(int r = 0; r < 8; r++) tile[t + 64*r][j] = v[r];
  }
  __syncthreads();

  #pragma unroll
  for(int h0 = 0; h0 < 512; h0 += 32){
    int h = h0 + (threadIdx.x >> 3), j = threadIdx.x & 7;
    base[(size_t)h * 512 + w0 + j] = tile[h][j];
  }
}

// ---------------- K3: row IFFT + add clean -> out ----------------
__global__ __launch_bounds__(256) void k_rowifft(const float2* __restrict__ ws,
                                                 const float* __restrict__ clean,
                                                 float* __restrict__ out){
  __shared__ cplx sbuf[4][512];
  int wid = threadIdx.x >> 6, t = threadIdx.x & 63;
  size_t row = (size_t)blockIdx.x * 4 + wid;
  const float2* ip = ws + row * 512;
  cplx v[8];
  #pragma unroll
  for(int r = 0; r < 8; r++) v[r] = ip[t + 64*r];
  fft512<1>(v, sbuf[wid], t);
  const float* cp_ = clean + row * 512;
  float* op = out + row * 512;
  #pragma unroll
  for(int r = 0; r < 8; r++) op[t + 64*r] = v[r].x + cp_[t + 64*r];
}

extern "C" void kernel_launch(void* const* d_in, const int* in_sizes, int n_in,
                              void* d_out, int out_size, void* d_ws, size_t ws_size,
                              hipStream_t stream){
  // setup_inputs order: clean, noisy, value_set  (all float32)
  const float* clean     = (const float*)d_in[0];
  const float* noisy     = (const float*)d_in[1];
  const float* value_set = (const float*)d_in[2];
  float* out = (float*)d_out;
  float2* ws = (float2*)d_ws;   // needs 48*512*512*8 = 100,663,296 B

  k_rowfft <<<6144, 256, 0, stream>>>(noisy, clean, ws);
  k_colfft <<<3072, 256, 0, stream>>>(ws, value_set);
  k_rowifft<<<6144, 256, 0, stream>>>(ws, clean, out);
}

// Round 4
// 227.787 us; speedup vs baseline: 1.1263x; 1.1263x over previous
//
#include <hip/hip_runtime.h>
#include <math.h>

// out = clean + IFFT2( mask_b ⊙ FFT2(noisy - clean) ), fftshifts cancelled into
// mask remap (fh = h<256 ? h : h-512; value_set row (b+8)&15).
//
// PACKING: mask is real, so two real images a,b pack as z = a + i·b.
// Z' (masked packed spectrum) = cs·Z + cd·conj(Z(-k)),  cs=(m1+m2)/2, cd=(m1-m2)/2.
// 24 packed images: p=0..15 -> (b,c0)+(b,c1) (m1=m2);  p=16..23 -> (2q,c2)+(2q+1,c2).
// ws = 24*512*512*8B = 50.3MB (L3-resident).
//
// K2 blocks own mirror column pairs so conj(Z(-k)) is wave-local:
// strip s>=1: slots {4s..4s+3} + {509-4s..512-4s}; strip 0: {0,1,2,3,509,510,511,256};
// pairing slot i <-> 7-i (strip0 slots 0,7 are SELF-paired: cols 0 and 256 —
// their fw^2 differ, so band radius is computed per stream, not per wave).

using cplx = float2;

__device__ __forceinline__ cplx cmul(cplx a, cplx b){
  return make_float2(a.x*b.x - a.y*b.y, a.x*b.y + a.y*b.x);
}
__device__ __forceinline__ cplx cadd(cplx a, cplx b){ return make_float2(a.x+b.x, a.y+b.y); }
__device__ __forceinline__ cplx csub(cplx a, cplx b){ return make_float2(a.x-b.x, a.y-b.y); }
template<int S> __device__ __forceinline__ cplx muli(cplx a){
  return (S < 0) ? make_float2(a.y, -a.x) : make_float2(-a.y, a.x);
}
// XOR swizzle on 512-entry scratch (bijection): breaks stride-8 bank conflicts.
__device__ __forceinline__ int sw(int i){ return i ^ (((i >> 6) & 7) << 1); }

template<int S>
__device__ __forceinline__ void dft8(cplx v[8]){
  const float R2 = 0.70710678118654752440f;
  cplx e0 = cadd(v[0], v[4]), e1 = csub(v[0], v[4]);
  cplx o0 = cadd(v[2], v[6]), o1 = muli<S>(csub(v[2], v[6]));
  cplx E0 = cadd(e0, o0), E1 = cadd(e1, o1), E2 = csub(e0, o0), E3 = csub(e1, o1);
  cplx f0 = cadd(v[1], v[5]), f1 = csub(v[1], v[5]);
  cplx g0 = cadd(v[3], v[7]), g1 = muli<S>(csub(v[3], v[7]));
  cplx F0 = cadd(f0, g0), F1 = cadd(f1, g1), F2 = csub(f0, g0), F3 = csub(f1, g1);
  const cplx w1 = make_float2( R2, (float)S * R2);
  const cplx w3 = make_float2(-R2, (float)S * R2);
  cplx t0 = F0, t1 = cmul(w1, F1), t2 = muli<S>(F2), t3 = cmul(w3, F3);
  v[0] = cadd(E0, t0); v[4] = csub(E0, t0);
  v[1] = cadd(E1, t1); v[5] = csub(E1, t1);
  v[2] = cadd(E2, t2); v[6] = csub(E2, t2);
  v[3] = cadd(E3, t3); v[7] = csub(E3, t3);
}

// shared-twiddle pair: one sincos serves both streams
template<int S>
__device__ __forceinline__ void twiddle8_pair(cplx a[8], cplx b[8], float ang){
  float sn, c_; __sincosf(ang, &sn, &c_);
  cplx w = make_float2(c_, sn), cur = w;
  #pragma unroll
  for(int r = 1; r < 8; r++){ a[r] = cmul(a[r], cur); b[r] = cmul(b[r], cur); cur = cmul(cur, w); }
}

// two interleaved 512-pt Stockham FFTs (ILP hides LDS latency chains).
// sa/sb: per-stream scratch bases, element stride STR (1 = flat, 9 = tile column).
template<int S, int STR>
__device__ __forceinline__ void fft512_pair(cplx a[8], cplx b[8], cplx* sa, cplx* sb, int t){
  const float PI2 = 6.283185307179586f;
  dft8<S>(a); dft8<S>(b);
  #pragma unroll
  for(int r = 0; r < 8; r++){ int i = sw(t*8 + r)*STR; sa[i] = a[r]; sb[i] = b[r]; }
  #pragma unroll
  for(int r = 0; r < 8; r++){ int i = sw(t + 64*r)*STR; a[r] = sa[i]; b[r] = sb[i]; }
  twiddle8_pair<S>(a, b, (float)S * PI2 * (1.0f/64.0f) * (float)(t & 7));
  dft8<S>(a); dft8<S>(b);
  int d1 = ((t >> 3) << 6) | (t & 7);
  #pragma unroll
  for(int r = 0; r < 8; r++){ int i = sw(d1 + (r << 3))*STR; sa[i] = a[r]; sb[i] = b[r]; }
  #pragma unroll
  for(int r = 0; r < 8; r++){ int i = sw(t + 64*r)*STR; a[r] = sa[i]; b[r] = sb[i]; }
  twiddle8_pair<S>(a, b, (float)S * PI2 * (1.0f/512.0f) * (float)t);
  dft8<S>(a); dft8<S>(b);
}

__device__ __forceinline__ void packed_images(int p, int& i0, int& i1, int& b1, int& b2){
  if (p < 16){ i0 = 3*p; i1 = 3*p + 1; b1 = p; b2 = p; }
  else { int q = p - 16; i0 = 6*q + 2; i1 = 6*q + 5; b1 = 2*q; b2 = 2*q + 1; }
}

__device__ __forceinline__ int slot_col(int s, int j){
  int c = (j < 4) ? (4*s + j) : (505 - 4*s + j);
  c &= 511;
  if (s == 0 && j == 7) c = 256;
  return c;
}

// ---------------- K1: packed row FFT of (noisy - clean) -> ws ----------------
__global__ __launch_bounds__(256) void k_rowfft(const float* __restrict__ noisy,
                                                const float* __restrict__ clean,
                                                float2* __restrict__ ws){
  __shared__ cplx scr[8][512];
  int blk = blockIdx.x;
  int p = blk >> 6, h8 = (blk & 63) << 3;
  int i0, i1, b1, b2; packed_images(p, i0, i1, b1, b2);
  const float* n0 = noisy + (size_t)i0 * 262144;
  const float* c0 = clean + (size_t)i0 * 262144;
  const float* n1 = noisy + (size_t)i1 * 262144;
  const float* c1 = clean + (size_t)i1 * 262144;
  int wid = threadIdx.x >> 6, t = threadIdx.x & 63;
  int hA = h8 + wid*2, hB = hA + 1;
  cplx a[8], b[8];
  #pragma unroll
  for(int r = 0; r < 8; r++){
    int iA = hA*512 + t + 64*r;
    int iB = hB*512 + t + 64*r;
    a[r] = make_float2(n0[iA]-c0[iA], n1[iA]-c1[iA]);
    b[r] = make_float2(n0[iB]-c0[iB], n1[iB]-c1[iB]);
  }
  fft512_pair<-1,1>(a, b, scr[wid*2], scr[wid*2+1], t);
  float2* oA = ws + (size_t)p*262144 + hA*512;
  float2* oB = ws + (size_t)p*262144 + hB*512;
  #pragma unroll
  for(int r = 0; r < 8; r++){ oA[t+64*r] = a[r]; oB[t+64*r] = b[r]; }
}

// ---- K2: col FFT + Hermitian-combine mask (*1/N^2) + col IFFT, in place ----
#define INV_BAND 0.27621358640099513f   // 100 / (sqrt(512^2+512^2)/2)

__global__ __launch_bounds__(256) void k_colfft(float2* __restrict__ ws,
                                                const float* __restrict__ value_set){
  __shared__ cplx tile[512][9];   // 8 column slots + pad; doubles as FFT scratch
  int blk = blockIdx.x;
  int p = blk >> 6, s = blk & 63;
  int i0, i1, b1, b2; packed_images(p, i0, i1, b1, b2);
  const float* vs1 = value_set + ((b1 + 8) & 15) * 100;
  const float* vs2 = value_set + ((b2 + 8) & 15) * 100;
  float2* base = ws + (size_t)p * 262144;
  int tid = threadIdx.x;

  { // cooperative coalesced load of the 8 columns
    int j = tid & 7, cj = slot_col(s, j);
    #pragma unroll
    for(int h0 = 0; h0 < 512; h0 += 32){
      int h = h0 + (tid >> 3);
      tile[h][j] = base[h*512 + cj];
    }
  }
  __syncthreads();

  int wid = tid >> 6, t = tid & 63;
  int sA = wid, sB = 7 - wid;                  // wave owns a mirror pair
  int colA = slot_col(s, sA);
  int colB = slot_col(s, sB);
  int fwA = (colA < 256) ? colA : colA - 512;
  int fwB = (colB < 256) ? colB : colB - 512;
  int fw2A = fwA * fwA;                        // per-stream: self-pair wave has
  int fw2B = fwB * fwB;                        // colA=0, colB=256 (differ!)
  bool selfp = (s == 0 && wid == 0);           // cols 0 and 256 self-mirror
  int pA = selfp ? sA : sB;                    // partner slot of A
  int pB = selfp ? sB : sA;

  cplx a[8], b[8];
  #pragma unroll
  for(int r = 0; r < 8; r++){ a[r] = tile[t+64*r][sA]; b[r] = tile[t+64*r][sB]; }
  fft512_pair<-1,9>(a, b, &tile[0][sA], &tile[0][sB], t);
  // park spectra in own columns (natural row order) for partner row-flip reads
  #pragma unroll
  for(int r = 0; r < 8; r++){ tile[t+64*r][sA] = a[r]; tile[t+64*r][sB] = b[r]; }
  // combine: Z' = cs*Z + cd*conj(Z(-k)); -k = (flip row, mirror col) = own wave's data
  #pragma unroll
  for(int r = 0; r < 8; r++){
    int h = t + 64*r;
    int fh = (h < 256) ? h : h - 512;
    int fh2 = fh * fh;
    float rrA = sqrtf((float)(fh2 + fw2A));
    float rrB = sqrtf((float)(fh2 + fw2B));
    int bandA = (int)(rrA * INV_BAND);
    int bandB = (int)(rrB * INV_BAND);
    float m1A = (bandA < 100) ? vs1[bandA] : 0.0f;
    float m2A = (bandA < 100) ? vs2[bandA] : 0.0f;
    float m1B = (bandB < 100) ? vs1[bandB] : 0.0f;
    float m2B = (bandB < 100) ? vs2[bandB] : 0.0f;
    float csA = 0.5f*(m1A + m2A) * (1.0f/262144.0f);
    float cdA = 0.5f*(m1A - m2A) * (1.0f/262144.0f);
    float csB = 0.5f*(m1B + m2B) * (1.0f/262144.0f);
    float cdB = 0.5f*(m1B - m2B) * (1.0f/262144.0f);
    int ph = (512 - h) & 511;
    float2 PA = tile[ph][pA];
    float2 PB = tile[ph][pB];
    cplx na = make_float2(csA*a[r].x + cdA*PA.x, csA*a[r].y - cdA*PA.y);
    cplx nb = make_float2(csB*b[r].x + cdB*PB.x, csB*b[r].y - cdB*PB.y);
    a[r] = na; b[r] = nb;
  }
  fft512_pair<1,9>(a, b, &tile[0][sA], &tile[0][sB], t);
  #pragma unroll
  for(int r = 0; r < 8; r++){ tile[t+64*r][sA] = a[r]; tile[t+64*r][sB] = b[r]; }
  __syncthreads();

  { // cooperative store back
    int j = tid & 7, cj = slot_col(s, j);
    #pragma unroll
    for(int h0 = 0; h0 < 512; h0 += 32){
      int h = h0 + (tid >> 3);
      base[h*512 + cj] = tile[h][j];
    }
  }
}

// ---------------- K3: packed row IFFT + add clean -> out ----------------
__global__ __launch_bounds__(256) void k_rowifft(const float2* __restrict__ ws,
                                                 const float* __restrict__ clean,
                                                 float* __restrict__ out){
  __shared__ cplx scr[8][512];
  int blk = blockIdx.x;
  int p = blk >> 6, h8 = (blk & 63) << 3;
  int i0, i1, b1, b2; packed_images(p, i0, i1, b1, b2);
  int wid = threadIdx.x >> 6, t = threadIdx.x & 63;
  int hA = h8 + wid*2, hB = hA + 1;
  const float2* iA_ = ws + (size_t)p*262144 + hA*512;
  const float2* iB_ = ws + (size_t)p*262144 + hB*512;
  cplx a[8], b[8];
  #pragma unroll
  for(int r = 0; r < 8; r++){ a[r] = iA_[t+64*r]; b[r] = iB_[t+64*r]; }
  fft512_pair<1,1>(a, b, scr[wid*2], scr[wid*2+1], t);
  const float* c0 = clean + (size_t)i0 * 262144;
  const float* c1 = clean + (size_t)i1 * 262144;
  float* o0 = out + (size_t)i0 * 262144;
  float* o1 = out + (size_t)i1 * 262144;
  #pragma unroll
  for(int r = 0; r < 8; r++){
    int iA = hA*512 + t + 64*r;
    int iB = hB*512 + t + 64*r;
    o0[iA] = a[r].x + c0[iA];
    o1[iA] = a[r].y + c1[iA];
    o0[iB] = b[r].x + c0[iB];
    o1[iB] = b[r].y + c1[iB];
  }
}

extern "C" void kernel_launch(void* const* d_in, const int* in_sizes, int n_in,
                              void* d_out, int out_size, void* d_ws, size_t ws_size,
                              hipStream_t stream){
  const float* clean     = (const float*)d_in[0];
  const float* noisy     = (const float*)d_in[1];
  const float* value_set = (const float*)d_in[2];
  float* out = (float*)d_out;
  float2* ws = (float2*)d_ws;   // 24*512*512*8 = 50,331,648 B

  k_rowfft <<<1536, 256, 0, stream>>>(noisy, clean, ws);
  k_colfft <<<1536, 256, 0, stream>>>(ws, value_set);
  k_rowifft<<<1536, 256, 0, stream>>>(ws, clean, out);
}

// Round 5
// 206.059 us; speedup vs baseline: 1.2451x; 1.1054x over previous
//
#include <hip/hip_runtime.h>
#include <math.h>

// out = clean + IFFT2( mask_b ⊙ FFT2(noisy - clean) ), fftshifts cancelled into
// mask remap (fh = h<256 ? h : h-512; value_set row (b+8)&15).
//
// PACKING: two real images a,b pack as z = a + i·b; masked spectrum
// Z' = cs·Z + cd·conj(Z(-k)), cs=(m1+m2)/2, cd=(m1-m2)/2.  24 pipelines:
// p<16 -> (b,c0)+(b,c1): m1==m2 -> cd=0 -> POINTWISE mask (no partner).
// p>=16 -> (2q,c2)+(2q+1,c2): cross-batch, needs Hermitian combine.
//
// FOLDED ws LAYOUT: K1 stores row-spectrum X[w] at column slot fold(w),
//   fold(w) = w<256 ? 2w : (w==256 ? 1 : 2*(512-w)+1)
// so mirror columns (w, 512-w) sit in ADJACENT slots. K2 blocks then read
// 16 contiguous slots = 8 mirror pairs = full 128-B lines (fixes the 2.2x
// over-fetch measured in R4: partner chunks were on different XCDs' L2s).
// K3 un-folds on load; stride-16B accesses pair up (r and 7-r) to cover
// full lines within one wave -> L1/L2 merge.

using cplx = float2;

__device__ __forceinline__ cplx cmul(cplx a, cplx b){
  return make_float2(a.x*b.x - a.y*b.y, a.x*b.y + a.y*b.x);
}
__device__ __forceinline__ cplx cadd(cplx a, cplx b){ return make_float2(a.x+b.x, a.y+b.y); }
__device__ __forceinline__ cplx csub(cplx a, cplx b){ return make_float2(a.x-b.x, a.y-b.y); }
template<int S> __device__ __forceinline__ cplx muli(cplx a){
  return (S < 0) ? make_float2(a.y, -a.x) : make_float2(-a.y, a.x);
}
// flat-scratch swizzle (K1/K3): bijection on 0..511, 4-way floor on b64 ops
__device__ __forceinline__ int sw(int i){ return i ^ (((i >> 6) & 7) << 1); }
// K2 tile addressing: 512 rows x 16 slots, XOR swizzle -> b64 bank floor on
// row-dense, col-dense, and FFT-exchange patterns. Bijective on 0..8191.
#define ADDR(i,j) (((i) << 4) + ((j) ^ ((((i) >> 3) ^ (((i) & 7) << 1)) & 15)))

__device__ __forceinline__ int fold(int w){
  return (w < 256) ? 2*w : ((w == 256) ? 1 : 2*(512 - w) + 1);
}

template<int S>
__device__ __forceinline__ void dft8(cplx v[8]){
  const float R2 = 0.70710678118654752440f;
  cplx e0 = cadd(v[0], v[4]), e1 = csub(v[0], v[4]);
  cplx o0 = cadd(v[2], v[6]), o1 = muli<S>(csub(v[2], v[6]));
  cplx E0 = cadd(e0, o0), E1 = cadd(e1, o1), E2 = csub(e0, o0), E3 = csub(e1, o1);
  cplx f0 = cadd(v[1], v[5]), f1 = csub(v[1], v[5]);
  cplx g0 = cadd(v[3], v[7]), g1 = muli<S>(csub(v[3], v[7]));
  cplx F0 = cadd(f0, g0), F1 = cadd(f1, g1), F2 = csub(f0, g0), F3 = csub(f1, g1);
  const cplx w1 = make_float2( R2, (float)S * R2);
  const cplx w3 = make_float2(-R2, (float)S * R2);
  cplx t0 = F0, t1 = cmul(w1, F1), t2 = muli<S>(F2), t3 = cmul(w3, F3);
  v[0] = cadd(E0, t0); v[4] = csub(E0, t0);
  v[1] = cadd(E1, t1); v[5] = csub(E1, t1);
  v[2] = cadd(E2, t2); v[6] = csub(E2, t2);
  v[3] = cadd(E3, t3); v[7] = csub(E3, t3);
}

template<int S>
__device__ __forceinline__ void twiddle8_pair(cplx a[8], cplx b[8], float ang){
  float sn, c_; __sincosf(ang, &sn, &c_);
  cplx w = make_float2(c_, sn), cur = w;
  #pragma unroll
  for(int r = 1; r < 8; r++){ a[r] = cmul(a[r], cur); b[r] = cmul(b[r], cur); cur = cmul(cur, w); }
}

// flat-scratch paired FFT (K1/K3)
template<int S>
__device__ __forceinline__ void fft512_pair(cplx a[8], cplx b[8], cplx* sa, cplx* sb, int t){
  const float PI2 = 6.283185307179586f;
  dft8<S>(a); dft8<S>(b);
  #pragma unroll
  for(int r = 0; r < 8; r++){ int i = sw(t*8 + r); sa[i] = a[r]; sb[i] = b[r]; }
  #pragma unroll
  for(int r = 0; r < 8; r++){ int i = sw(t + 64*r); a[r] = sa[i]; b[r] = sb[i]; }
  twiddle8_pair<S>(a, b, (float)S * PI2 * (1.0f/64.0f) * (float)(t & 7));
  dft8<S>(a); dft8<S>(b);
  int d1 = ((t >> 3) << 6) | (t & 7);
  #pragma unroll
  for(int r = 0; r < 8; r++){ int i = sw(d1 + (r << 3)); sa[i] = a[r]; sb[i] = b[r]; }
  #pragma unroll
  for(int r = 0; r < 8; r++){ int i = sw(t + 64*r); a[r] = sa[i]; b[r] = sb[i]; }
  twiddle8_pair<S>(a, b, (float)S * PI2 * (1.0f/512.0f) * (float)t);
  dft8<S>(a); dft8<S>(b);
}

// tile-scratch paired FFT (K2): scratch = wave's own two column slots
template<int S>
__device__ __forceinline__ void fft512_pair_tile(cplx a[8], cplx b[8], cplx* T, int jA, int jB, int t){
  const float PI2 = 6.283185307179586f;
  dft8<S>(a); dft8<S>(b);
  #pragma unroll
  for(int r = 0; r < 8; r++){ int i = t*8 + r; T[ADDR(i,jA)] = a[r]; T[ADDR(i,jB)] = b[r]; }
  #pragma unroll
  for(int r = 0; r < 8; r++){ int i = t + 64*r; a[r] = T[ADDR(i,jA)]; b[r] = T[ADDR(i,jB)]; }
  twiddle8_pair<S>(a, b, (float)S * PI2 * (1.0f/64.0f) * (float)(t & 7));
  dft8<S>(a); dft8<S>(b);
  int d1 = ((t >> 3) << 6) | (t & 7);
  #pragma unroll
  for(int r = 0; r < 8; r++){ int i = d1 + (r << 3); T[ADDR(i,jA)] = a[r]; T[ADDR(i,jB)] = b[r]; }
  #pragma unroll
  for(int r = 0; r < 8; r++){ int i = t + 64*r; a[r] = T[ADDR(i,jA)]; b[r] = T[ADDR(i,jB)]; }
  twiddle8_pair<S>(a, b, (float)S * PI2 * (1.0f/512.0f) * (float)t);
  dft8<S>(a); dft8<S>(b);
}

__device__ __forceinline__ void packed_images(int p, int& i0, int& i1, int& b1, int& b2){
  if (p < 16){ i0 = 3*p; i1 = 3*p + 1; b1 = p; b2 = p; }
  else { int q = p - 16; i0 = 6*q + 2; i1 = 6*q + 5; b1 = 2*q; b2 = 2*q + 1; }
}

// ---------------- K1: packed row FFT of (noisy - clean) -> folded ws ----------------
__global__ __launch_bounds__(256, 5) void k_rowfft(const float* __restrict__ noisy,
                                                   const float* __restrict__ clean,
                                                   float2* __restrict__ ws){
  __shared__ cplx scr[8][512];
  int blk = blockIdx.x;
  int p = blk >> 6, h8 = (blk & 63) << 3;
  int i0, i1, b1, b2; packed_images(p, i0, i1, b1, b2);
  const float* n0 = noisy + (size_t)i0 * 262144;
  const float* c0 = clean + (size_t)i0 * 262144;
  const float* n1 = noisy + (size_t)i1 * 262144;
  const float* c1 = clean + (size_t)i1 * 262144;
  int wid = threadIdx.x >> 6, t = threadIdx.x & 63;
  int hA = h8 + wid*2, hB = hA + 1;
  cplx a[8], b[8];
  #pragma unroll
  for(int r = 0; r < 8; r++){
    int iA = hA*512 + t + 64*r;
    int iB = hB*512 + t + 64*r;
    a[r] = make_float2(n0[iA]-c0[iA], n1[iA]-c1[iA]);
    b[r] = make_float2(n0[iB]-c0[iB], n1[iB]-c1[iB]);
  }
  fft512_pair<-1>(a, b, scr[wid*2], scr[wid*2+1], t);
  float2* oA = ws + (size_t)p*262144 + hA*512;
  float2* oB = ws + (size_t)p*262144 + hB*512;
  #pragma unroll
  for(int r = 0; r < 8; r++){
    int s = fold(t + 64*r);         // r and 7-r stores cover even/odd of each line
    oA[s] = a[r]; oB[s] = b[r];
  }
}

// ---- K2: col FFT + mask (+Hermitian combine for cross pairs) + col IFFT ----
#define INV_BAND 0.27621358640099513f   // 100 / (sqrt(512^2+512^2)/2)

__global__ __launch_bounds__(512) void k_colfft(float2* __restrict__ ws,
                                                const float* __restrict__ value_set){
  __shared__ cplx tile[512 * 16];   // 64 KB, swizzled via ADDR
  int blk = blockIdx.x;
  int p = blk >> 5, m = blk & 31;              // 16-slot group per block
  int i0, i1, b1, b2; packed_images(p, i0, i1, b1, b2);
  const float* vs1 = value_set + ((b1 + 8) & 15) * 100;
  const float* vs2 = value_set + ((b2 + 8) & 15) * 100;
  bool cross = (p >= 16);
  float2* base = ws + (size_t)p * 262144 + 16*m;
  int tid = threadIdx.x;

  { // coop load: 16 contiguous slots = full 128-B lines per row
    int j = tid & 15, hb = tid >> 4;
    #pragma unroll
    for(int h0 = 0; h0 < 512; h0 += 32){
      int h = h0 + hb;
      tile[ADDR(h, j)] = base[(size_t)h * 512 + j];
    }
  }
  __syncthreads();

  int wid = tid >> 6, t = tid & 63;
  int jA = wid*2, jB = wid*2 + 1;              // adjacent slots = mirror pair
  int SA = 16*m + jA;                          // global even slot
  int wA = SA >> 1;                            // natural col of A, in [0,255]
  int fw2A = wA * wA;
  int fw2B = (SA == 0) ? 65536 : wA * wA;      // slot1 = col 256 (self-mirror)
  bool selfp = (SA == 0);                      // cols 0 & 256: each self-paired
  int pjA = selfp ? jA : jB;                   // partner slot of A's column
  int pjB = selfp ? jB : jA;

  cplx a[8], b[8];
  #pragma unroll
  for(int r = 0; r < 8; r++){ int i = t + 64*r; a[r] = tile[ADDR(i,jA)]; b[r] = tile[ADDR(i,jB)]; }
  fft512_pair_tile<-1>(a, b, tile, jA, jB, t);

  if (cross){
    // park spectra (natural row order) for partner row-flip reads
    #pragma unroll
    for(int r = 0; r < 8; r++){ int i = t + 64*r; tile[ADDR(i,jA)] = a[r]; tile[ADDR(i,jB)] = b[r]; }
    #pragma unroll
    for(int r = 0; r < 8; r++){
      int h = t + 64*r;
      int fh = (h < 256) ? h : h - 512;
      int fh2 = fh * fh;
      int bandA = (int)(sqrtf((float)(fh2 + fw2A)) * INV_BAND);
      int bandB = (int)(sqrtf((float)(fh2 + fw2B)) * INV_BAND);
      float m1A = (bandA < 100) ? vs1[bandA] : 0.0f;
      float m2A = (bandA < 100) ? vs2[bandA] : 0.0f;
      float m1B = (bandB < 100) ? vs1[bandB] : 0.0f;
      float m2B = (bandB < 100) ? vs2[bandB] : 0.0f;
      float csA = 0.5f*(m1A + m2A) * (1.0f/262144.0f);
      float cdA = 0.5f*(m1A - m2A) * (1.0f/262144.0f);
      float csB = 0.5f*(m1B + m2B) * (1.0f/262144.0f);
      float cdB = 0.5f*(m1B - m2B) * (1.0f/262144.0f);
      int ph = (512 - h) & 511;
      float2 PA = tile[ADDR(ph, pjA)];
      float2 PB = tile[ADDR(ph, pjB)];
      a[r] = make_float2(csA*a[r].x + cdA*PA.x, csA*a[r].y - cdA*PA.y);
      b[r] = make_float2(csB*b[r].x + cdB*PB.x, csB*b[r].y - cdB*PB.y);
    }
  } else {
    // same mask for both packed images: pointwise scale, no partner needed
    #pragma unroll
    for(int r = 0; r < 8; r++){
      int h = t + 64*r;
      int fh = (h < 256) ? h : h - 512;
      int fh2 = fh * fh;
      int bandA = (int)(sqrtf((float)(fh2 + fw2A)) * INV_BAND);
      int bandB = (int)(sqrtf((float)(fh2 + fw2B)) * INV_BAND);
      float mA = (bandA < 100) ? vs1[bandA] : 0.0f;
      float mB = (bandB < 100) ? vs1[bandB] : 0.0f;
      float csA = mA * (1.0f/262144.0f);
      float csB = mB * (1.0f/262144.0f);
      a[r].x *= csA; a[r].y *= csA;
      b[r].x *= csB; b[r].y *= csB;
    }
  }

  fft512_pair_tile<1>(a, b, tile, jA, jB, t);
  #pragma unroll
  for(int r = 0; r < 8; r++){ int i = t + 64*r; tile[ADDR(i,jA)] = a[r]; tile[ADDR(i,jB)] = b[r]; }
  __syncthreads();

  { // coop store back (dense lines)
    int j = tid & 15, hb = tid >> 4;
    #pragma unroll
    for(int h0 = 0; h0 < 512; h0 += 32){
      int h = h0 + hb;
      base[(size_t)h * 512 + j] = tile[ADDR(h, j)];
    }
  }
}

// ---------------- K3: packed row IFFT (folded input) + add clean -> out ----------------
__global__ __launch_bounds__(256, 5) void k_rowifft(const float2* __restrict__ ws,
                                                    const float* __restrict__ clean,
                                                    float* __restrict__ out){
  __shared__ cplx scr[8][512];
  int blk = blockIdx.x;
  int p = blk >> 6, h8 = (blk & 63) << 3;
  int i0, i1, b1, b2; packed_images(p, i0, i1, b1, b2);
  int wid = threadIdx.x >> 6, t = threadIdx.x & 63;
  int hA = h8 + wid*2, hB = hA + 1;
  const float2* iA_ = ws + (size_t)p*262144 + hA*512;
  const float2* iB_ = ws + (size_t)p*262144 + hB*512;
  cplx a[8], b[8];
  #pragma unroll
  for(int r = 0; r < 8; r++){
    int s = fold(t + 64*r);         // r and 7-r loads L1-pair on the same lines
    a[r] = iA_[s]; b[r] = iB_[s];
  }
  fft512_pair<1>(a, b, scr[wid*2], scr[wid*2+1], t);
  const float* c0 = clean + (size_t)i0 * 262144;
  const float* c1 = clean + (size_t)i1 * 262144;
  float* o0 = out + (size_t)i0 * 262144;
  float* o1 = out + (size_t)i1 * 262144;
  #pragma unroll
  for(int r = 0; r < 8; r++){
    int iA = hA*512 + t + 64*r;
    int iB = hB*512 + t + 64*r;
    o0[iA] = a[r].x + c0[iA];
    o1[iA] = a[r].y + c1[iA];
    o0[iB] = b[r].x + c0[iB];
    o1[iB] = b[r].y + c1[iB];
  }
}

extern "C" void kernel_launch(void* const* d_in, const int* in_sizes, int n_in,
                              void* d_out, int out_size, void* d_ws, size_t ws_size,
                              hipStream_t stream){
  const float* clean     = (const float*)d_in[0];
  const float* noisy     = (const float*)d_in[1];
  const float* value_set = (const float*)d_in[2];
  float* out = (float*)d_out;
  float2* ws = (float2*)d_ws;   // 24*512*512*8 = 50,331,648 B

  k_rowfft <<<1536, 256, 0, stream>>>(noisy, clean, ws);
  k_colfft <<< 768, 512, 0, stream>>>(ws, value_set);
  k_rowifft<<<1536, 256, 0, stream>>>(ws, clean, out);
}